// Round 9
// baseline (15.542 us; speedup 1.0000x reference)
//
#include <hip/hip_runtime.h>

// WKV power kernel, R9 = R7 (measured best, 10.03 us): single dispatch,
// 16 blocks x 1024 threads (16 waves). Block = 16 dims (one full 64B line)
// -> every global access touches fully-used lines (4 lines per wave-instr).
// Thread (c,dd): dd = t&15 dim-in-block, c = t>>4 chunk of 16 rows.
// Scan: per-chunk affine carries via padded LDS; wave w Kogge-Stones dim w's
// 64 carries. R8's T-split/flag-lookback variant measured SLOWER (11.96) --
// cross-block sync costs exceed the <=1.3 us of addressable kernel time.

constexpr int T  = 1024;
constexpr int D  = 256;
constexpr int GD = 16;        // dims per block = one 64B line
constexpr int RT = 16;        // rows per thread
constexpr int NCH = T / RT;   // 64 chunks per dim
constexpr int NTH = NCH * GD; // 1024 threads = 16 waves

__global__ __launch_bounds__(NTH) void wkv_scan_kernel(
    const float* __restrict__ k, const float* __restrict__ v,
    const float* __restrict__ time_first, const float* __restrict__ time_decay,
    float* __restrict__ out)
{
    __shared__ float cK[NCH][GD + 1];   // +1 pad: scan reads column-wise
    __shared__ float cV[NCH][GD + 1];

    const int t  = threadIdx.x;
    const int dd = t & (GD - 1);
    const int c  = t >> 4;              // chunk 0..63
    const int d  = blockIdx.x * GD + dd;

    const float td = time_decay[d];
    const float wd = __expf(td);        // per-row decay

    // ---- Phase 1: coalesced load + local recurrence seeded 0 ----
    const int base = c * RT;
    float kx[RT], vx[RT];
    float bk = 0.f, bv = 0.f;
#pragma unroll
    for (int j = 0; j < RT; ++j) {
        const float kk = k[(base + j) * D + d];   // 4 fully-used lines/instr
        const float vv = v[(base + j) * D + d];
        const float e  = __expf(kk);
        kx[j] = e;
        vx[j] = vv * e;
        bk = wd * (e + bk);             // s <- w*(x + s)
        bv = wd * (vx[j] + bv);
    }
    cK[c][dd] = bk;
    cV[c][dd] = bv;
    __syncthreads();

    // ---- Phase 2: wave w scans dim (blk*16 + w); lane = chunk ----
    {
        const int w    = t >> 6;        // wave id 0..15 == dim-in-block
        const int lane = t & 63;
        const float tdw = time_decay[blockIdx.x * GD + w];  // wave-uniform

        float sbk = cK[lane][w];        // stride-17 floats: 2-way bank = free
        float sbv = cV[lane][w];

        // Kogge-Stone inclusive; uniform chunk multiplier m = w^RT,
        // o-span factor f = m^o (f *= f each step).
        float f = __expf(tdw * (float)RT);
#pragma unroll
        for (int o = 1; o < 64; o <<= 1) {
            const float pk = __shfl_up(sbk, o);
            const float pv = __shfl_up(sbv, o);
            if (lane >= o) {
                sbk = fmaf(f, pk, sbk);
                sbv = fmaf(f, pv, sbv);
            }
            f = f * f;
        }
        // Exclusive prefix = state entering chunk `lane`; write back in place
        // (each wave touches only its own column w -> no cross-wave hazard).
        float ek = __shfl_up(sbk, 1);
        float ev = __shfl_up(sbv, 1);
        if (lane == 0) { ek = 0.f; ev = 0.f; }
        cK[lane][w] = ek;
        cV[lane][w] = ev;
    }
    __syncthreads();

    // ---- Phase 3: seed with prefix; reuse register kx/vx; fused output ----
    const float tf = __expf(time_first[d]);
    float sk = cK[c][dd];
    float sv = cV[c][dd];
#pragma unroll
    for (int j = 0; j < RT; ++j) {
        sk = wd * (kx[j] + sk);                 // = kxr[i]
        sv = wd * (vx[j] + sv);                 // = vxr[i]
        const float num = fmaf(vx[j], tf, sk);  // vx*tf + kxr (faithful swap)
        const float den = fmaf(kx[j], tf, sv);  // kx*tf + vxr
        out[(base + j) * D + d] = num * __builtin_amdgcn_rcpf(den);  // coalesced
    }
}

extern "C" void kernel_launch(void* const* d_in, const int* in_sizes, int n_in,
                              void* d_out, int out_size, void* d_ws, size_t ws_size,
                              hipStream_t stream) {
    const float* k  = (const float*)d_in[0];
    const float* v  = (const float*)d_in[1];
    const float* tf = (const float*)d_in[2];
    const float* td = (const float*)d_in[3];
    float* out = (float*)d_out;

    dim3 grid(D / GD);             // 16 blocks, 16 dims each
    dim3 block(NTH);               // 1024 threads = 16 waves
    wkv_scan_kernel<<<grid, block, 0, stream>>>(k, v, tf, td, out);
}